// Round 2
// baseline (285.560 us; speedup 1.0000x reference)
//
#include <hip/hip_runtime.h>
#include <stdint.h>

#define DIMC 1024
#define NSEQ 4096
#define NH 16

typedef __attribute__((ext_vector_type(8))) short bf16x8;
typedef __attribute__((ext_vector_type(4))) float f32x4;

__device__ __forceinline__ unsigned short f2bf(float x) {
    union { float f; unsigned int u; } v; v.f = x;
    unsigned int u = v.u;
    return (unsigned short)((u + 0x7fffu + ((u >> 16) & 1u)) >> 16);
}

// ---- content fp32 -> bf16 ----
__global__ __launch_bounds__(256) void k_conv(const float* __restrict__ in,
                                              unsigned short* __restrict__ out) {
    int i = (blockIdx.x * 256 + threadIdx.x) * 8;
    float4 a = *reinterpret_cast<const float4*>(in + i);
    float4 b = *reinterpret_cast<const float4*>(in + i + 4);
    union { unsigned short us[8]; uint4 v; } r;
    r.us[0] = f2bf(a.x); r.us[1] = f2bf(a.y); r.us[2] = f2bf(a.z); r.us[3] = f2bf(a.w);
    r.us[4] = f2bf(b.x); r.us[5] = f2bf(b.y); r.us[6] = f2bf(b.z); r.us[7] = f2bf(b.w);
    *reinterpret_cast<uint4*>(out + i) = r.v;
}

// ---- W fp32 -> bf16, transposed (Wt[n][k] = W[k][n]) ----
__global__ __launch_bounds__(1024) void k_wt(const float* __restrict__ Wq,
                                             const float* __restrict__ Wk,
                                             const float* __restrict__ Wv,
                                             unsigned short* __restrict__ wt) {
    __shared__ float tile[32][33];
    int z = blockIdx.z;
    const float* W = (z == 0) ? Wq : ((z == 1) ? Wk : Wv);
    int n0 = blockIdx.x * 32, k0 = blockIdx.y * 32;
    tile[threadIdx.y][threadIdx.x] = W[(k0 + threadIdx.y) * DIMC + n0 + threadIdx.x];
    __syncthreads();
    wt[(size_t)z * DIMC * DIMC + (n0 + threadIdx.y) * DIMC + k0 + threadIdx.x] =
        f2bf(tile[threadIdx.x][threadIdx.y]);
}

// ---- QKV GEMM: C = A(bf16 4096x1024) * Wt^T ; z=0->Q, z=1->K, z=2->V stored transposed ----
__global__ __launch_bounds__(256) void k_gemm(const unsigned short* __restrict__ A,
                                              const unsigned short* __restrict__ Wt,
                                              unsigned short* __restrict__ Qb,
                                              unsigned short* __restrict__ Kb,
                                              unsigned short* __restrict__ Vt) {
    __shared__ unsigned short As[128][40];   // +8 pad: 2-way-conflict-free b128 reads
    __shared__ unsigned short Bs[128][40];
    const int z = blockIdx.z;
    const unsigned short* Wz = Wt + (size_t)z * DIMC * DIMC;
    const int n0 = blockIdx.x * 128, m0 = blockIdx.y * 128;
    const int t = threadIdx.x;
    const int w = t >> 6, l = t & 63;
    const int wr = w >> 1, wc = w & 1;
    const int lq = l & 15, lg = l >> 4;
    const int srow = t >> 1, sch = (t & 1) * 16;

    f32x4 acc[4][4];
    #pragma unroll
    for (int i = 0; i < 4; ++i)
        #pragma unroll
        for (int j = 0; j < 4; ++j)
            acc[i][j] = f32x4{0.f, 0.f, 0.f, 0.f};

    for (int k0 = 0; k0 < DIMC; k0 += 32) {
        uint4 va0 = *reinterpret_cast<const uint4*>(A  + (m0 + srow) * DIMC + k0 + sch);
        uint4 va1 = *reinterpret_cast<const uint4*>(A  + (m0 + srow) * DIMC + k0 + sch + 8);
        uint4 vb0 = *reinterpret_cast<const uint4*>(Wz + (n0 + srow) * DIMC + k0 + sch);
        uint4 vb1 = *reinterpret_cast<const uint4*>(Wz + (n0 + srow) * DIMC + k0 + sch + 8);
        __syncthreads();
        *reinterpret_cast<uint4*>(&As[srow][sch])     = va0;
        *reinterpret_cast<uint4*>(&As[srow][sch + 8]) = va1;
        *reinterpret_cast<uint4*>(&Bs[srow][sch])     = vb0;
        *reinterpret_cast<uint4*>(&Bs[srow][sch + 8]) = vb1;
        __syncthreads();
        bf16x8 af[4], bfr[4];
        #pragma unroll
        for (int mf = 0; mf < 4; ++mf)
            af[mf] = *reinterpret_cast<const bf16x8*>(&As[wr * 64 + mf * 16 + lq][lg * 8]);
        #pragma unroll
        for (int nf = 0; nf < 4; ++nf)
            bfr[nf] = *reinterpret_cast<const bf16x8*>(&Bs[wc * 64 + nf * 16 + lq][lg * 8]);
        #pragma unroll
        for (int mf = 0; mf < 4; ++mf)
            #pragma unroll
            for (int nf = 0; nf < 4; ++nf)
                acc[mf][nf] = __builtin_amdgcn_mfma_f32_16x16x32_bf16(af[mf], bfr[nf], acc[mf][nf], 0, 0, 0);
    }

    if (z < 2) {
        unsigned short* out = (z == 0) ? Qb : Kb;
        #pragma unroll
        for (int mf = 0; mf < 4; ++mf)
            #pragma unroll
            for (int nf = 0; nf < 4; ++nf)
                #pragma unroll
                for (int j = 0; j < 4; ++j) {
                    int row = m0 + wr * 64 + mf * 16 + lg * 4 + j;
                    int col = n0 + wc * 64 + nf * 16 + lq;
                    out[row * DIMC + col] = f2bf(acc[mf][nf][j]);
                }
    } else {
        // V transposed: Vt[d][n], d in [0,1024), n in [0,4096)
        #pragma unroll
        for (int mf = 0; mf < 4; ++mf)
            #pragma unroll
            for (int nf = 0; nf < 4; ++nf) {
                int row  = n0 + wc * 64 + nf * 16 + lq;       // d index
                int colb = m0 + wr * 64 + mf * 16 + lg * 4;   // seq index (4-aligned)
                uint2 pk;
                pk.x = (unsigned)f2bf(acc[mf][nf][0]) | ((unsigned)f2bf(acc[mf][nf][1]) << 16);
                pk.y = (unsigned)f2bf(acc[mf][nf][2]) | ((unsigned)f2bf(acc[mf][nf][3]) << 16);
                *reinterpret_cast<uint2*>(Vt + (size_t)row * NSEQ + colb) = pk;
            }
    }
}

// ---- fused attention: full-row softmax denominator, causal numerator (post-softmax tril) ----
__global__ __launch_bounds__(256) void k_attn(const unsigned short* __restrict__ Qb,
                                              const unsigned short* __restrict__ Kb,
                                              const unsigned short* __restrict__ Vt,
                                              float* __restrict__ Y) {
    __shared__ unsigned short Ks[64][72];      // [k][d], +8 pad
    __shared__ unsigned short Vs[64][72];      // [d][k], +8 pad (from pre-transposed Vt)
    __shared__ unsigned short Ps[4][16][72];   // per-wave P bounce: [wave][q][k]
    const int qb = blockIdx.x, h = blockIdx.y;
    const int t = threadIdx.x;
    const int w = t >> 6, l = t & 63;
    const int lq = l & 15, lg = l >> 4;

    // Q B-fragment, hoisted: lane holds Q[w*16+lq][lg*8 + i (+32)]
    bf16x8 qf0, qf1;
    {
        const unsigned short* qp = Qb + (qb * 64 + w * 16 + lq) * DIMC + h * 64 + lg * 8;
        qf0 = *reinterpret_cast<const bf16x8*>(qp);
        qf1 = *reinterpret_cast<const bf16x8*>(qp + 32);
    }
    float m_st = -__builtin_inff(), l_st = 0.f;
    float m_pv = -__builtin_inff();            // frame of O (max at last PV tile)
    f32x4 O[4];
    #pragma unroll
    for (int df = 0; df < 4; ++df) O[df] = f32x4{0.f, 0.f, 0.f, 0.f};

    const int r0 = t >> 3, c0 = (t & 7) * 8;   // staging: 2 chunks of 8 elems per thread

    for (int kt = 0; kt < 64; ++kt) {
        const bool pv = (kt <= qb);            // tiles above diagonal: denominator only
        uint4 kv0 = *reinterpret_cast<const uint4*>(Kb + (kt * 64 + r0) * DIMC + h * 64 + c0);
        uint4 kv1 = *reinterpret_cast<const uint4*>(Kb + (kt * 64 + 32 + r0) * DIMC + h * 64 + c0);
        uint4 vv0, vv1;
        if (pv) {
            vv0 = *reinterpret_cast<const uint4*>(Vt + (size_t)(h * 64 + r0) * NSEQ + kt * 64 + c0);
            vv1 = *reinterpret_cast<const uint4*>(Vt + (size_t)(h * 64 + 32 + r0) * NSEQ + kt * 64 + c0);
        }
        __syncthreads();
        *reinterpret_cast<uint4*>(&Ks[r0][c0])      = kv0;
        *reinterpret_cast<uint4*>(&Ks[32 + r0][c0]) = kv1;
        if (pv) {
            *reinterpret_cast<uint4*>(&Vs[r0][c0])      = vv0;
            *reinterpret_cast<uint4*>(&Vs[32 + r0][c0]) = vv1;
        }
        __syncthreads();

        // swapped QK^T: S^T[k][q] = mfma(A=K, B=Q); lane holds k = f*16 + lg*4 + j, q = w*16+lq
        f32x4 s[4];
        #pragma unroll
        for (int f = 0; f < 4; ++f) {
            s[f] = f32x4{0.f, 0.f, 0.f, 0.f};
            bf16x8 ka0 = *reinterpret_cast<const bf16x8*>(&Ks[f * 16 + lq][lg * 8]);
            bf16x8 ka1 = *reinterpret_cast<const bf16x8*>(&Ks[f * 16 + lq][32 + lg * 8]);
            s[f] = __builtin_amdgcn_mfma_f32_16x16x32_bf16(ka0, qf0, s[f], 0, 0, 0);
            s[f] = __builtin_amdgcn_mfma_f32_16x16x32_bf16(ka1, qf1, s[f], 0, 0, 0);
        }
        float tmax = -__builtin_inff();
        #pragma unroll
        for (int f = 0; f < 4; ++f)
            #pragma unroll
            for (int j = 0; j < 4; ++j) {
                s[f][j] *= 0.125f;                    // 1/sqrt(64)
                tmax = fmaxf(tmax, s[f][j]);
            }
        tmax = fmaxf(tmax, __shfl_xor(tmax, 16));
        tmax = fmaxf(tmax, __shfl_xor(tmax, 32));
        const float mnew = fmaxf(m_st, tmax);
        const float sc = __expf(m_st - mnew);         // first tile: exp(-inf)=0
        m_st = mnew;
        float p[4][4];
        float psum = 0.f;
        #pragma unroll
        for (int f = 0; f < 4; ++f)
            #pragma unroll
            for (int j = 0; j < 4; ++j) {
                p[f][j] = __expf(s[f][j] - mnew);     // UNMASKED: denominator over all k
                psum += p[f][j];
            }
        psum += __shfl_xor(psum, 16);
        psum += __shfl_xor(psum, 32);
        l_st = l_st * sc + psum;

        if (pv) {
            // During the PV prefix m_pv == m_st(old), so sc is also O's rescale factor.
            m_pv = mnew;
            // rescale O (O rows are lg*4+j; scale lives at lane q)
            #pragma unroll
            for (int j = 0; j < 4; ++j) {
                const float scj = __shfl(sc, lg * 4 + j);
                #pragma unroll
                for (int df = 0; df < 4; ++df) O[df][j] *= scj;
            }
            // mask (post-softmax tril) + pack P^T frag (4 consecutive k) to per-wave LDS
            const bool edge = (kt == qb);
            #pragma unroll
            for (int f = 0; f < 4; ++f) {
                float v0 = p[f][0], v1 = p[f][1], v2 = p[f][2], v3 = p[f][3];
                if (edge) {
                    const int kbase = f * 16 + lg * 4, qrel = w * 16 + lq;
                    if (kbase + 0 > qrel) v0 = 0.f;
                    if (kbase + 1 > qrel) v1 = 0.f;
                    if (kbase + 2 > qrel) v2 = 0.f;
                    if (kbase + 3 > qrel) v3 = 0.f;
                }
                uint2 pk;
                pk.x = (unsigned)f2bf(v0) | ((unsigned)f2bf(v1) << 16);
                pk.y = (unsigned)f2bf(v2) | ((unsigned)f2bf(v3) << 16);
                *reinterpret_cast<uint2*>(&Ps[w][lq][f * 16 + lg * 4]) = pk;
            }
            // PV: O[q][d] += P[q][k] * V[k][d]
            #pragma unroll
            for (int kk = 0; kk < 2; ++kk) {
                bf16x8 pa = *reinterpret_cast<const bf16x8*>(&Ps[w][lq][kk * 32 + lg * 8]);
                #pragma unroll
                for (int df = 0; df < 4; ++df) {
                    bf16x8 vb = *reinterpret_cast<const bf16x8*>(&Vs[df * 16 + lq][kk * 32 + lg * 8]);
                    O[df] = __builtin_amdgcn_mfma_f32_16x16x32_bf16(pa, vb, O[df], 0, 0, 0);
                }
            }
        }
    }

    // epilogue: O is in frame m_pv (max at last PV tile); denominator l_st is in frame
    // m_st (full-row max). Correct by exp(m_pv - m_st), then divide by l_st.
    const float corr = __expf(m_pv - m_st) / l_st;    // per-q, valid at lanes where q == lq
    #pragma unroll
    for (int j = 0; j < 4; ++j) {
        const float li = __shfl(corr, lg * 4 + j);
        #pragma unroll
        for (int df = 0; df < 4; ++df)
            Y[(qb * 64 + w * 16 + lg * 4 + j) * DIMC + h * 64 + df * 16 + lq] = O[df][j] * li;
    }
}

extern "C" void kernel_launch(void* const* d_in, const int* in_sizes, int n_in,
                              void* d_out, int out_size, void* d_ws, size_t ws_size,
                              hipStream_t stream) {
    const float* content = (const float*)d_in[0];
    const float* Wq = (const float*)d_in[1];
    const float* Wk = (const float*)d_in[2];
    const float* Wv = (const float*)d_in[3];
    float* Y = (float*)d_out;
    unsigned short* ws  = (unsigned short*)d_ws;
    unsigned short* cbf = ws;                                   // content bf16   (4M elems)
    unsigned short* wt  = cbf + (size_t)NSEQ * DIMC;            // Wt bf16 x3     (3M elems)
    unsigned short* qb  = wt  + (size_t)3 * DIMC * DIMC;        // Q bf16         (4M elems)
    unsigned short* kb  = qb  + (size_t)NSEQ * DIMC;            // K bf16         (4M elems)
    unsigned short* vt  = kb  + (size_t)NSEQ * DIMC;            // V^T bf16       (4M elems)

    hipLaunchKernelGGL(k_conv, dim3(NSEQ * DIMC / (256 * 8)), dim3(256), 0, stream, content, cbf);
    hipLaunchKernelGGL(k_wt,   dim3(32, 32, 3), dim3(32, 32), 0, stream, Wq, Wk, Wv, wt);
    hipLaunchKernelGGL(k_gemm, dim3(DIMC / 128, NSEQ / 128, 3), dim3(256), 0, stream, cbf, wt, qb, kb, vt);
    hipLaunchKernelGGL(k_attn, dim3(NSEQ / 64, NH), dim3(256), 0, stream, qb, kb, vt, Y);
}

// Round 3
// 258.695 us; speedup vs baseline: 1.1038x; 1.1038x over previous
//
#include <hip/hip_runtime.h>
#include <stdint.h>

#define DIMC 1024
#define NSEQ 4096
#define NH 16
#define QSCALE 0.18033688011112042f   // 0.125 * log2(e): scores come out in exp2 domain

typedef __attribute__((ext_vector_type(8))) short bf16x8;
typedef __attribute__((ext_vector_type(4))) float f32x4;

__device__ __forceinline__ unsigned short f2bf(float x) {
    union { float f; unsigned int u; } v; v.f = x;
    unsigned int u = v.u;
    return (unsigned short)((u + 0x7fffu + ((u >> 16) & 1u)) >> 16);
}

__device__ __forceinline__ unsigned cvt_pk_bf16(float lo, float hi) {
    unsigned r;
    asm("v_cvt_pk_bf16_f32 %0, %1, %2" : "=v"(r) : "v"(lo), "v"(hi));
    return r;
}

__device__ __forceinline__ void gload16(const unsigned short* g, unsigned short* l) {
    __builtin_amdgcn_global_load_lds(
        (const __attribute__((address_space(1))) void*)g,
        (__attribute__((address_space(3))) void*)l, 16, 0, 0);
}

// ---- content fp32 -> bf16 ----
__global__ __launch_bounds__(256) void k_conv(const float* __restrict__ in,
                                              unsigned short* __restrict__ out) {
    int i = (blockIdx.x * 256 + threadIdx.x) * 8;
    float4 a = *reinterpret_cast<const float4*>(in + i);
    float4 b = *reinterpret_cast<const float4*>(in + i + 4);
    union { unsigned short us[8]; uint4 v; } r;
    r.us[0] = f2bf(a.x); r.us[1] = f2bf(a.y); r.us[2] = f2bf(a.z); r.us[3] = f2bf(a.w);
    r.us[4] = f2bf(b.x); r.us[5] = f2bf(b.y); r.us[6] = f2bf(b.z); r.us[7] = f2bf(b.w);
    *reinterpret_cast<uint4*>(out + i) = r.v;
}

// ---- W fp32 -> bf16, transposed (Wt[n][k] = W[k][n]) ----
__global__ __launch_bounds__(1024) void k_wt(const float* __restrict__ Wq,
                                             const float* __restrict__ Wk,
                                             const float* __restrict__ Wv,
                                             unsigned short* __restrict__ wt) {
    __shared__ float tile[32][33];
    int z = blockIdx.z;
    const float* W = (z == 0) ? Wq : ((z == 1) ? Wk : Wv);
    int n0 = blockIdx.x * 32, k0 = blockIdx.y * 32;
    tile[threadIdx.y][threadIdx.x] = W[(k0 + threadIdx.y) * DIMC + n0 + threadIdx.x];
    __syncthreads();
    wt[(size_t)z * DIMC * DIMC + (n0 + threadIdx.y) * DIMC + k0 + threadIdx.x] =
        f2bf(tile[threadIdx.x][threadIdx.y]);
}

// ---- QKV GEMM (m97 structure: global_load_lds w16, linear LDS) ----
// z=0 -> Q (pre-scaled by QSCALE), z=1 -> K, z=2 -> V stored transposed Vt[d][n]
__global__ __launch_bounds__(256) void k_gemm(const unsigned short* __restrict__ A,
                                              const unsigned short* __restrict__ Wt,
                                              unsigned short* __restrict__ Qb,
                                              unsigned short* __restrict__ Kb,
                                              unsigned short* __restrict__ Vt) {
    __shared__ unsigned short As[128 * 32];   // linear, row-major [128][32] (global_load_lds)
    __shared__ unsigned short Bs[128 * 32];
    const int z = blockIdx.z;
    const unsigned short* Wz = Wt + (size_t)z * DIMC * DIMC;
    const int n0 = blockIdx.x * 128, m0 = blockIdx.y * 128;
    const int t = threadIdx.x;
    const int w = t >> 6, l = t & 63;
    const int wr = w >> 1, wc = w & 1;
    const int lq = l & 15, lg = l >> 4;
    // staging: wave w covers rows w*32..w*32+31 via 2 chunks of 16 rows.
    // lane l: row = chunk*16 + l/4, col = (l&3)*8  (lds dst = base + lane*16 automatic)
    const int srow = l >> 2, scol = (l & 3) * 8;
    const unsigned short* gA = A  + (size_t)(m0 + w * 32 + srow) * DIMC + scol;
    const unsigned short* gB = Wz + (size_t)(n0 + w * 32 + srow) * DIMC + scol;
    unsigned short* lA = &As[(2 * w) * 512];
    unsigned short* lB = &Bs[(2 * w) * 512];

    f32x4 acc[4][4];
    #pragma unroll
    for (int i = 0; i < 4; ++i)
        #pragma unroll
        for (int j = 0; j < 4; ++j)
            acc[i][j] = f32x4{0.f, 0.f, 0.f, 0.f};

    for (int k0 = 0; k0 < DIMC; k0 += 32) {
        __syncthreads();
        gload16(gA + k0, lA);
        gload16(gA + k0 + 16 * DIMC, lA + 512);
        gload16(gB + k0, lB);
        gload16(gB + k0 + 16 * DIMC, lB + 512);
        __syncthreads();
        bf16x8 af[4], bfr[4];
        #pragma unroll
        for (int mf = 0; mf < 4; ++mf)
            af[mf] = *reinterpret_cast<const bf16x8*>(&As[(wr * 64 + mf * 16 + lq) * 32 + lg * 8]);
        #pragma unroll
        for (int nf = 0; nf < 4; ++nf)
            bfr[nf] = *reinterpret_cast<const bf16x8*>(&Bs[(wc * 64 + nf * 16 + lq) * 32 + lg * 8]);
        __builtin_amdgcn_s_setprio(1);
        #pragma unroll
        for (int mf = 0; mf < 4; ++mf)
            #pragma unroll
            for (int nf = 0; nf < 4; ++nf)
                acc[mf][nf] = __builtin_amdgcn_mfma_f32_16x16x32_bf16(af[mf], bfr[nf], acc[mf][nf], 0, 0, 0);
        __builtin_amdgcn_s_setprio(0);
    }

    if (z < 2) {
        unsigned short* out = (z == 0) ? Qb : Kb;
        const float osc = (z == 0) ? QSCALE : 1.0f;
        #pragma unroll
        for (int mf = 0; mf < 4; ++mf)
            #pragma unroll
            for (int nf = 0; nf < 4; ++nf)
                #pragma unroll
                for (int j = 0; j < 4; ++j) {
                    int row = m0 + wr * 64 + mf * 16 + lg * 4 + j;
                    int col = n0 + wc * 64 + nf * 16 + lq;
                    out[row * DIMC + col] = f2bf(acc[mf][nf][j] * osc);
                }
    } else {
        #pragma unroll
        for (int mf = 0; mf < 4; ++mf)
            #pragma unroll
            for (int nf = 0; nf < 4; ++nf) {
                int row  = n0 + wc * 64 + nf * 16 + lq;       // d index
                int colb = m0 + wr * 64 + mf * 16 + lg * 4;   // seq index (4-aligned)
                uint2 pk;
                pk.x = cvt_pk_bf16(acc[mf][nf][0], acc[mf][nf][1]);
                pk.y = cvt_pk_bf16(acc[mf][nf][2], acc[mf][nf][3]);
                *reinterpret_cast<uint2*>(Vt + (size_t)row * NSEQ + colb) = pk;
            }
    }
}

// ---- fused attention: paired q-tiles (bx, 63-bx), 8 waves, exp2-domain defer-max softmax ----
__global__ __launch_bounds__(512, 4) void k_attn(const unsigned short* __restrict__ Qb,
                                                 const unsigned short* __restrict__ Kb,
                                                 const unsigned short* __restrict__ Vt,
                                                 float* __restrict__ Y) {
    __shared__ unsigned short Ks[64][72];      // [k][d], stride 36 dw (uniform-bank b128 reads)
    __shared__ unsigned short Vs[64][72];      // [d][k]
    __shared__ unsigned short Ps[8][16][88];   // per-wave P bounce; stride 44 dw (~2-way writes)
    const int bx = blockIdx.x, h = blockIdx.y;
    const int t = threadIdx.x;
    const int w = t >> 6, l = t & 63;
    const int wq = w & 3, tile = w >> 2;
    const int lq = l & 15, lg = l >> 4;
    const int qbA = bx, qbB = 63 - bx;         // qbA < qbB; per-block PV tiles = 65 (uniform)
    const int qb_my = tile ? qbB : qbA;

    // Q B-fragment (already scaled by QSCALE in k_gemm)
    bf16x8 qf0, qf1;
    {
        const unsigned short* qp = Qb + (size_t)(qb_my * 64 + wq * 16 + lq) * DIMC + h * 64 + lg * 8;
        qf0 = *reinterpret_cast<const bf16x8*>(qp);
        qf1 = *reinterpret_cast<const bf16x8*>(qp + 32);
    }
    float m_fr = -__builtin_inff(), l_st = 0.f;
    f32x4 O[4];
    #pragma unroll
    for (int df = 0; df < 4; ++df) O[df] = f32x4{0.f, 0.f, 0.f, 0.f};

    // staging: 512 threads x one uint4 each covers a full 64x64 bf16 tile
    const int r0 = t >> 3, c0 = (t & 7) * 8;
    const unsigned short* gK = Kb + (size_t)r0 * DIMC + h * 64 + c0;
    const unsigned short* gV = Vt + (size_t)(h * 64 + r0) * NSEQ + c0;

    uint4 kv = *reinterpret_cast<const uint4*>(gK);     // kt = 0
    uint4 vv = *reinterpret_cast<const uint4*>(gV);     // kt = 0 always <= qbB

    for (int kt = 0; kt < 64; ++kt) {
        __syncthreads();
        *reinterpret_cast<uint4*>(&Ks[r0][c0]) = kv;
        if (kt <= qbB) *reinterpret_cast<uint4*>(&Vs[r0][c0]) = vv;
        __syncthreads();
        if (kt < 63) {                                   // T14: issue next-tile loads, hide under compute
            kv = *reinterpret_cast<const uint4*>(gK + (size_t)(kt + 1) * 64 * DIMC);
            if (kt + 1 <= qbB) vv = *reinterpret_cast<const uint4*>(gV + (kt + 1) * 64);
        }

        // swapped QK^T: lane holds t2[k = f*16+lg*4+j][q = wq*16+lq], exp2 domain
        f32x4 s[4];
        __builtin_amdgcn_s_setprio(1);
        #pragma unroll
        for (int f = 0; f < 4; ++f) {
            s[f] = f32x4{0.f, 0.f, 0.f, 0.f};
            bf16x8 ka0 = *reinterpret_cast<const bf16x8*>(&Ks[f * 16 + lq][lg * 8]);
            bf16x8 ka1 = *reinterpret_cast<const bf16x8*>(&Ks[f * 16 + lq][32 + lg * 8]);
            s[f] = __builtin_amdgcn_mfma_f32_16x16x32_bf16(ka0, qf0, s[f], 0, 0, 0);
            s[f] = __builtin_amdgcn_mfma_f32_16x16x32_bf16(ka1, qf1, s[f], 0, 0, 0);
        }
        __builtin_amdgcn_s_setprio(0);

        float tmax = s[0][0];
        #pragma unroll
        for (int f = 0; f < 4; ++f)
            #pragma unroll
            for (int j = 0; j < 4; ++j) tmax = fmaxf(tmax, s[f][j]);
        tmax = fmaxf(tmax, __shfl_xor(tmax, 16));
        tmax = fmaxf(tmax, __shfl_xor(tmax, 32));

        // T13 defer-max: only rescale when the frame is exceeded by >8 (exp2 units, P <= 256)
        if (!__all(tmax <= m_fr + 8.f)) {
            const float mnew = fmaxf(m_fr, tmax);
            const float sc = exp2f(m_fr - mnew);         // first tile: exp2(-inf) = 0
            l_st *= sc;
            #pragma unroll
            for (int j = 0; j < 4; ++j) {
                const float scj = __shfl(sc, lg * 4 + j);
                #pragma unroll
                for (int df = 0; df < 4; ++df) O[df][j] *= scj;
            }
            m_fr = mnew;
        }
        float psum = 0.f;
        #pragma unroll
        for (int f = 0; f < 4; ++f)
            #pragma unroll
            for (int j = 0; j < 4; ++j) {
                const float p = exp2f(s[f][j] - m_fr);   // UNMASKED: denominator over all k
                s[f][j] = p;
                psum += p;
            }
        psum += __shfl_xor(psum, 16);
        psum += __shfl_xor(psum, 32);
        l_st += psum;

        if (kt <= qb_my) {
            // post-softmax tril mask on the diagonal tile, then T12 cvt_pk packing
            if (kt == qb_my) {
                const int qrel = wq * 16 + lq;
                #pragma unroll
                for (int f = 0; f < 4; ++f) {
                    const int kbase = f * 16 + lg * 4;
                    #pragma unroll
                    for (int j = 0; j < 4; ++j)
                        if (kbase + j > qrel) s[f][j] = 0.f;
                }
            }
            #pragma unroll
            for (int f = 0; f < 4; ++f) {
                uint2 pk;
                pk.x = cvt_pk_bf16(s[f][0], s[f][1]);
                pk.y = cvt_pk_bf16(s[f][2], s[f][3]);
                *reinterpret_cast<uint2*>(&Ps[w][lq][f * 16 + lg * 4]) = pk;
            }
            __builtin_amdgcn_s_setprio(1);
            #pragma unroll
            for (int kk = 0; kk < 2; ++kk) {
                bf16x8 pa = *reinterpret_cast<const bf16x8*>(&Ps[w][lq][kk * 32 + lg * 8]);
                #pragma unroll
                for (int df = 0; df < 4; ++df) {
                    bf16x8 vb = *reinterpret_cast<const bf16x8*>(&Vs[df * 16 + lq][kk * 32 + lg * 8]);
                    O[df] = __builtin_amdgcn_mfma_f32_16x16x32_bf16(pa, vb, O[df], 0, 0, 0);
                }
            }
            __builtin_amdgcn_s_setprio(0);
        }
    }

    // O and l share the same frame m_fr (O rescaled on every frame change) -> Y = O / l
    const float rl = 1.0f / l_st;
    #pragma unroll
    for (int j = 0; j < 4; ++j) {
        const float li = __shfl(rl, lg * 4 + j);
        #pragma unroll
        for (int df = 0; df < 4; ++df)
            Y[(qb_my * 64 + wq * 16 + lg * 4 + j) * DIMC + h * 64 + df * 16 + lq] = O[df][j] * li;
    }
}

extern "C" void kernel_launch(void* const* d_in, const int* in_sizes, int n_in,
                              void* d_out, int out_size, void* d_ws, size_t ws_size,
                              hipStream_t stream) {
    const float* content = (const float*)d_in[0];
    const float* Wq = (const float*)d_in[1];
    const float* Wk = (const float*)d_in[2];
    const float* Wv = (const float*)d_in[3];
    float* Y = (float*)d_out;
    unsigned short* ws  = (unsigned short*)d_ws;
    unsigned short* cbf = ws;                                   // content bf16   (4M elems)
    unsigned short* wt  = cbf + (size_t)NSEQ * DIMC;            // Wt bf16 x3     (3M elems)
    unsigned short* qb  = wt  + (size_t)3 * DIMC * DIMC;        // Q bf16 (pre-scaled)
    unsigned short* kb  = qb  + (size_t)NSEQ * DIMC;            // K bf16
    unsigned short* vt  = kb  + (size_t)NSEQ * DIMC;            // V^T bf16

    hipLaunchKernelGGL(k_conv, dim3(NSEQ * DIMC / (256 * 8)), dim3(256), 0, stream, content, cbf);
    hipLaunchKernelGGL(k_wt,   dim3(32, 32, 3), dim3(32, 32), 0, stream, Wq, Wk, Wv, wt);
    hipLaunchKernelGGL(k_gemm, dim3(DIMC / 128, NSEQ / 128, 3), dim3(256), 0, stream, cbf, wt, qb, kb, vt);
    hipLaunchKernelGGL(k_attn, dim3(NSEQ / 128, NH), dim3(512), 0, stream, qb, kb, vt, Y);
}